// Round 9
// baseline (162.821 us; speedup 1.0000x reference)
//
#include <hip/hip_runtime.h>

#define K_CW 256
#define PPT 8       // points per thread
#define NQ 4        // split-K quarters
#define KQ (K_CW / NQ)  // 64 k per quarter

struct P8 { float4 a; float4 b; };  // {c0,c1,c2,c3} {csq,pad,pad,pad} -> one s_load_dwordx8

// Build packed codebook in ws. csq uses numpy rounding:
// ((c0*c0 + c1*c1) + c2*c2) + c3*c3  (sequential adds of rounded squares)
__global__ void vq_pack_kernel(const float* __restrict__ tlut, float* __restrict__ pk) {
    int k = threadIdx.x;  // 256 threads, 1 block
    float c0 = tlut[k * 4 + 0];
    float c1 = tlut[k * 4 + 1];
    float c2 = tlut[k * 4 + 2];
    float c3 = tlut[k * 4 + 3];
    float s = __fadd_rn(__fadd_rn(__fadd_rn(__fmul_rn(c0, c0), __fmul_rn(c1, c1)),
                                  __fmul_rn(c2, c2)),
                        __fmul_rn(c3, c3));
    pk[k * 8 + 0] = c0; pk[k * 8 + 1] = c1; pk[k * 8 + 2] = c2; pk[k * 8 + 3] = c3;
    pk[k * 8 + 4] = s;  pk[k * 8 + 5] = 0.f; pk[k * 8 + 6] = 0.f; pk[k * 8 + 7] = 0.f;
}

__global__ __launch_bounds__(1024, 8) void vq_argmin_kernel(
    const float* __restrict__ X,
    const float* __restrict__ tlut,
    const float* __restrict__ pk,
    float* __restrict__ outX,   // [B,4] reconstruction
    float* __restrict__ outS,   // [B] state, stored as float
    int B) {
    // split-K x4: quarter q scans k in [64q, 64q+64) on the same 8 points.
    // PPT=8 amortizes per-k fixed overhead over 8 chains; 512 blocks x 16
    // waves keep 32 waves/CU (needs VGPR<=64 -> launch_bounds(.,8)).
    __shared__ float sdv[3 * 256 * PPT];  // quarters 1..3 bestd (24 KB)
    __shared__ int   siv[3 * 256 * PPT];  // quarters 1..3 besti (24 KB)

    const int t = threadIdx.x;
    const int tt = t & 255;
    const int q = t >> 8;  // wave-uniform (wave = 64 consecutive threads)
    const int kbase = __builtin_amdgcn_readfirstlane(q << 6);

    const int g = blockIdx.x * 256 + tt;   // point-group id
    const int stride = B / PPT;            // 131072: strided points -> coalesced

    const float4* __restrict__ X4 = reinterpret_cast<const float4*>(X);
    const float4* __restrict__ T4 = reinterpret_cast<const float4*>(tlut);
    const P8* __restrict__ PK = reinterpret_cast<const P8*>(pk);

    float x0[PPT], x1[PPT], x2[PPT], x3[PPT], xsq[PPT], bestd[PPT];
    int besti[PPT];

    #pragma unroll
    for (int i = 0; i < PPT; ++i) {
        const float4 xv = X4[g + i * stride];
        x0[i] = xv.x; x1[i] = xv.y; x2[i] = xv.z; x3[i] = xv.w;
        // x_sq with numpy rounding: sequential adds of rounded squares
        xsq[i] = __fadd_rn(__fadd_rn(__fadd_rn(__fmul_rn(xv.x, xv.x), __fmul_rn(xv.y, xv.y)),
                                     __fmul_rn(xv.z, xv.z)),
                           __fmul_rn(xv.w, xv.w));
        bestd[i] = __builtin_inff();
        besti[i] = kbase;
    }

    #pragma unroll 8
    for (int kk = 0; kk < KQ; ++kk) {
        const int k = kbase + kk;          // wave-uniform -> scalar path
        const P8 e = PK[k];                // one s_load_dwordx8 per k
        const float4 c = e.a;
        const float cs = e.b.x;
        #pragma unroll
        for (int i = 0; i < PPT; ++i) {
            // cross: numpy einsum `accum += a*b` with fp-contract -> ascending FMA chain
            float cross = __fmul_rn(x0[i], c.x);
            cross = __fmaf_rn(x1[i], c.y, cross);
            cross = __fmaf_rn(x2[i], c.z, cross);
            cross = __fmaf_rn(x3[i], c.w, cross);
            // (x_sq - 2*cross) + c_sq ; fma(-2,cross,xsq) == rn(xsq - rn(2*cross)) exactly
            float t2 = __fmaf_rn(-2.0f, cross, xsq[i]);
            float d = __fadd_rn(t2, cs);
            // argmin, first occurrence (strict <), ascending k:
            // index via cmp+cndmask, value via v_min (independent ops)
            besti[i] = (d < bestd[i]) ? k : besti[i];
            bestd[i] = fminf(d, bestd[i]);
        }
    }

    if (q > 0) {
        float* sdst = &sdv[((q - 1) * 256 + tt) * PPT];
        int*   idst = &siv[((q - 1) * 256 + tt) * PPT];
        #pragma unroll
        for (int i = 0; i < PPT; ++i) { sdst[i] = bestd[i]; idst[i] = besti[i]; }
    }
    __syncthreads();
    if (q == 0) {
        // merge quarters ascending in k; strict '<' -> smaller k wins ties
        // (np.argmin first-occurrence)
        #pragma unroll
        for (int j = 0; j < 3; ++j) {
            const float* ssrc = &sdv[(j * 256 + tt) * PPT];
            const int*   isrc = &siv[(j * 256 + tt) * PPT];
            #pragma unroll
            for (int i = 0; i < PPT; ++i) {
                const float od = ssrc[i];
                const int   oi = isrc[i];
                if (od < bestd[i]) { bestd[i] = od; besti[i] = oi; }
            }
        }
        #pragma unroll
        for (int i = 0; i < PPT; ++i) {
            const int p = g + i * stride;
            reinterpret_cast<float4*>(outX)[p] = T4[besti[i]];
            outS[p] = (float)besti[i];
        }
    }
}

extern "C" void kernel_launch(void* const* d_in, const int* in_sizes, int n_in,
                              void* d_out, int out_size, void* d_ws, size_t ws_size,
                              hipStream_t stream) {
    const float* X    = (const float*)d_in[0];   // [B,4]
    const float* tlut = (const float*)d_in[1];   // [256,4]
    const int B = in_sizes[0] / 4;

    float* outX = (float*)d_out;          // first B*4 floats: hatX
    float* outS = outX + (size_t)B * 4;   // next B floats: state (as float)

    float* pk = (float*)d_ws;             // 256*8 floats packed codebook

    vq_pack_kernel<<<1, 256, 0, stream>>>(tlut, pk);

    const int groups = B / PPT;           // 131072 point-groups
    const int grid = groups / 256;        // 512 blocks of 1024 threads
    vq_argmin_kernel<<<grid, 1024, 0, stream>>>(X, tlut, pk, outX, outS, B);
}

// Round 10
// 117.721 us; speedup vs baseline: 1.3831x; 1.3831x over previous
//
#include <hip/hip_runtime.h>

#define K_CW 256
#define PPT 8        // points per thread
#define NQ 4         // split-K quarters
#define KQ (K_CW / NQ)   // 64 k per quarter
#define GPB 128      // point-groups per block (512 threads = NQ*GPB)

struct P8 { float4 a; float4 b; };  // {c0,c1,c2,c3} {csq,pad,pad,pad} -> one s_load_dwordx8

// Build packed codebook in ws. csq uses numpy rounding:
// ((c0*c0 + c1*c1) + c2*c2) + c3*c3  (sequential adds of rounded squares)
__global__ void vq_pack_kernel(const float* __restrict__ tlut, float* __restrict__ pk) {
    int k = threadIdx.x;  // 256 threads, 1 block
    float c0 = tlut[k * 4 + 0];
    float c1 = tlut[k * 4 + 1];
    float c2 = tlut[k * 4 + 2];
    float c3 = tlut[k * 4 + 3];
    float s = __fadd_rn(__fadd_rn(__fadd_rn(__fmul_rn(c0, c0), __fmul_rn(c1, c1)),
                                  __fmul_rn(c2, c2)),
                        __fmul_rn(c3, c3));
    pk[k * 8 + 0] = c0; pk[k * 8 + 1] = c1; pk[k * 8 + 2] = c2; pk[k * 8 + 3] = c3;
    pk[k * 8 + 4] = s;  pk[k * 8 + 5] = 0.f; pk[k * 8 + 6] = 0.f; pk[k * 8 + 7] = 0.f;
}

// NOTE: no min-waves arg — R9 showed a tight bound forces VGPR=32 + scratch
// spills for PPT=8 state (~60 regs). Let the allocator pick; target <=64.
__global__ __launch_bounds__(512) void vq_argmin_kernel(
    const float* __restrict__ X,
    const float* __restrict__ tlut,
    const float* __restrict__ pk,
    float* __restrict__ outX,   // [B,4] reconstruction
    float* __restrict__ outS,   // [B] state, stored as float
    int B) {
    // split-K x4: quarter q scans k in [64q,64q+64) on the same 8 points.
    // 1024 blocks x 512 thr = 524288 threads = exactly 32 waves/CU resident
    // (4 blocks/CU, 24 KB LDS each).
    __shared__ float sdv[3 * GPB * PPT];  // quarters 1..3 bestd (12 KB)
    __shared__ int   siv[3 * GPB * PPT];  // quarters 1..3 besti (12 KB)

    const int t = threadIdx.x;
    const int tt = t & (GPB - 1);
    const int q = t >> 7;  // 4 quarters of 128 thr = 2 waves each -> wave-uniform
    const int kbase = __builtin_amdgcn_readfirstlane(q << 6);

    const int g = blockIdx.x * GPB + tt;   // point-group id
    const int stride = B / PPT;            // 131072: strided points -> coalesced

    const float4* __restrict__ X4 = reinterpret_cast<const float4*>(X);
    const float4* __restrict__ T4 = reinterpret_cast<const float4*>(tlut);
    const P8* __restrict__ PK = reinterpret_cast<const P8*>(pk);

    float x0[PPT], x1[PPT], x2[PPT], x3[PPT], xsq[PPT], bestd[PPT];
    int besti[PPT];

    #pragma unroll
    for (int i = 0; i < PPT; ++i) {
        const float4 xv = X4[g + i * stride];
        x0[i] = xv.x; x1[i] = xv.y; x2[i] = xv.z; x3[i] = xv.w;
        // x_sq with numpy rounding: sequential adds of rounded squares
        xsq[i] = __fadd_rn(__fadd_rn(__fadd_rn(__fmul_rn(xv.x, xv.x), __fmul_rn(xv.y, xv.y)),
                                     __fmul_rn(xv.z, xv.z)),
                           __fmul_rn(xv.w, xv.w));
        bestd[i] = __builtin_inff();
        besti[i] = kbase;
    }

    #pragma unroll 8
    for (int kk = 0; kk < KQ; ++kk) {
        const int k = kbase + kk;          // wave-uniform -> scalar path
        const P8 e = PK[k];                // one s_load_dwordx8 per k
        const float4 c = e.a;
        const float cs = e.b.x;
        #pragma unroll
        for (int i = 0; i < PPT; ++i) {
            // cross: numpy einsum `accum += a*b` with fp-contract -> ascending FMA chain
            float cross = __fmul_rn(x0[i], c.x);
            cross = __fmaf_rn(x1[i], c.y, cross);
            cross = __fmaf_rn(x2[i], c.z, cross);
            cross = __fmaf_rn(x3[i], c.w, cross);
            // (x_sq - 2*cross) + c_sq ; fma(-2,cross,xsq) == rn(xsq - rn(2*cross)) exactly
            float t2 = __fmaf_rn(-2.0f, cross, xsq[i]);
            float d = __fadd_rn(t2, cs);
            // argmin, first occurrence (strict <), ascending k:
            // index via cmp+cndmask, value via v_min (independent ops)
            besti[i] = (d < bestd[i]) ? k : besti[i];
            bestd[i] = fminf(d, bestd[i]);
        }
    }

    if (q > 0) {
        float* sdst = &sdv[((q - 1) * GPB + tt) * PPT];
        int*   idst = &siv[((q - 1) * GPB + tt) * PPT];
        #pragma unroll
        for (int i = 0; i < PPT; ++i) { sdst[i] = bestd[i]; idst[i] = besti[i]; }
    }
    __syncthreads();
    if (q == 0) {
        // merge quarters ascending in k; strict '<' -> smaller k wins ties
        // (np.argmin first-occurrence)
        #pragma unroll
        for (int j = 0; j < 3; ++j) {
            const float* ssrc = &sdv[(j * GPB + tt) * PPT];
            const int*   isrc = &siv[(j * GPB + tt) * PPT];
            #pragma unroll
            for (int i = 0; i < PPT; ++i) {
                const float od = ssrc[i];
                const int   oi = isrc[i];
                if (od < bestd[i]) { bestd[i] = od; besti[i] = oi; }
            }
        }
        #pragma unroll
        for (int i = 0; i < PPT; ++i) {
            const int p = g + i * stride;
            reinterpret_cast<float4*>(outX)[p] = T4[besti[i]];
            outS[p] = (float)besti[i];
        }
    }
}

extern "C" void kernel_launch(void* const* d_in, const int* in_sizes, int n_in,
                              void* d_out, int out_size, void* d_ws, size_t ws_size,
                              hipStream_t stream) {
    const float* X    = (const float*)d_in[0];   // [B,4]
    const float* tlut = (const float*)d_in[1];   // [256,4]
    const int B = in_sizes[0] / 4;

    float* outX = (float*)d_out;          // first B*4 floats: hatX
    float* outS = outX + (size_t)B * 4;   // next B floats: state (as float)

    float* pk = (float*)d_ws;             // 256*8 floats packed codebook

    vq_pack_kernel<<<1, 256, 0, stream>>>(tlut, pk);

    const int groups = B / PPT;           // 131072 point-groups
    const int grid = groups / GPB;        // 1024 blocks of 512 threads
    vq_argmin_kernel<<<grid, 512, 0, stream>>>(X, tlut, pk, outX, outS, B);
}